// Round 1
// baseline (155.555 us; speedup 1.0000x reference)
//
#include <hip/hip_runtime.h>

// LayerHypercube: out[b, f*1024+o] = sum_j x[b, o^(1<<j)] * w[f,j,o] + bias[f,o] + x[b,o]
// B=2048, F=16, O=I=1024, BITS=10. fm analytic (o^(1<<j)) -- not read.
//
// R4 theory: kernel (~72 us of the 154; remainder is the timed 512 MiB re-poison
// fill) is HBM-bound ABOVE the 143 MB mandatory traffic because the 134 MB
// streaming write thrashes L2, evicting the staged x chunks (41 MB logical) and
// per-block w re-reads (84 MB logical) back to HBM/LLC.
// Fix A: non-temporal output stores -> write stream is evict-first, L2 keeps x/w.
// Fix B: XCD-grouped swizzle -> all 16 chunk-blocks of a btile co-resident on one
// XCD; per-XCD read footprint (x 1 MB + w 0.64 MB) fits the 4 MB local L2.
//
// Per block (chunk c, BTILE=16 rows, 2 waves x 8f): LDS holds [row][slot][64]
// slots = chunks {c, c^1, c^2, c^4, c^8} (20 KB). Gather j=0..5 = LDS read at
// lane^(1<<j) (bank-permutation, conflict-free); j=6..9 = slot 1..4 at lane.
// Stores: 256 B contiguous per wave instruction, 8 per row, nontemporal.

#define BTILE 16
#define NSLOT 5

__global__ __launch_bounds__(128, 2) void hypercube_kernel(
    const float* __restrict__ x,      // [2048][1024]
    const float* __restrict__ w,      // [16][10][1024]
    const float* __restrict__ bias,   // [16][1024]
    float* __restrict__ out)          // [2048][16*1024]
{
    __shared__ float xs[BTILE * NSLOT * 64];   // 20 KB: [row][slot][lane]

    const int tid   = threadIdx.x;
    const int lane  = tid & 63;
    const int wave  = tid >> 6;          // 0..1

    // XCD-grouped swizzle (bijective: 2048 blocks = 8 XCD x 16 btile x 16 chunk).
    // Dispatch round-robins blockIdx over 8 XCDs, so bid&7 pins the XCD; all 16
    // chunks of a btile land on the same XCD and share x via its L2.
    const int bid   = blockIdx.x;
    const int xcd   = bid & 7;
    const int ix    = bid >> 3;          // 0..255 within this XCD
    const int btile = xcd * 16 + (ix >> 4);
    const int chunk = ix & 15;

    const int b0    = btile * BTILE;
    const int f0    = wave * 8;
    const int o     = chunk * 64 + lane;

    // ---- Burst-stage BTILE rows x 5 chunks (1280 float4, 10 per thread) ----
    // slot s holds chunk ^ {0,1,2,4,8} = chunk ^ ((1<<s)>>1).
    #pragma unroll
    for (int it = 0; it < (BTILE * NSLOT * 64 / 4) / 128; ++it) {
        const int q    = it * 128 + tid;        // float4 index
        const int row  = q / (NSLOT * 16);      // 80 float4 per row
        const int rem  = q - row * (NSLOT * 16);
        const int slot = rem >> 4;              // 16 float4 per slot
        const int l4   = (rem & 15) << 2;
        const int src_chunk = chunk ^ ((1 << slot) >> 1);
        const float4 v = *(const float4*)&x[(size_t)(b0 + row) * 1024 + src_chunk * 64 + l4];
        *(float4*)&xs[q * 4] = v;
    }

    // ---- Weights for 8 f's at this lane's o (independent of staging) ----
    float wr[8][10], br[8];
    #pragma unroll
    for (int ff = 0; ff < 8; ++ff) {
        const int f = f0 + ff;
        #pragma unroll
        for (int j = 0; j < 10; ++j)
            wr[ff][j] = w[(f * 10 + j) * 1024 + o];
        br[ff] = bias[f * 1024 + o];
    }

    __syncthreads();

    // ---- Pure LDS + FMA + nontemporal-store loop: no global loads ----
    #pragma unroll 2
    for (int row = 0; row < BTILE; ++row) {
        const float* __restrict__ xr = &xs[row * (NSLOT * 64)];
        const float x0 = xr[lane];
        const float g0 = xr[lane ^ 1];
        const float g1 = xr[lane ^ 2];
        const float g2 = xr[lane ^ 4];
        const float g3 = xr[lane ^ 8];
        const float g4 = xr[lane ^ 16];
        const float g5 = xr[lane ^ 32];
        const float g6 = xr[64  + lane];   // o ^ 64
        const float g7 = xr[128 + lane];   // o ^ 128
        const float g8 = xr[192 + lane];   // o ^ 256
        const float g9 = xr[256 + lane];   // o ^ 512

        float* __restrict__ ob = out + (size_t)(b0 + row) * 16384 + chunk * 64 + lane;
        #pragma unroll
        for (int ff = 0; ff < 8; ++ff) {
            float acc = br[ff] + x0;          // bias + tiled-x term
            acc = fmaf(g0, wr[ff][0], acc);
            acc = fmaf(g1, wr[ff][1], acc);
            acc = fmaf(g2, wr[ff][2], acc);
            acc = fmaf(g3, wr[ff][3], acc);
            acc = fmaf(g4, wr[ff][4], acc);
            acc = fmaf(g5, wr[ff][5], acc);
            acc = fmaf(g6, wr[ff][6], acc);
            acc = fmaf(g7, wr[ff][7], acc);
            acc = fmaf(g8, wr[ff][8], acc);
            acc = fmaf(g9, wr[ff][9], acc);
            __builtin_nontemporal_store(acc, &ob[(f0 + ff) * 1024]);  // 256 B/wave-instr, evict-first
        }
    }
}

extern "C" void kernel_launch(void* const* d_in, const int* in_sizes, int n_in,
                              void* d_out, int out_size, void* d_ws, size_t ws_size,
                              hipStream_t stream) {
    const float* x    = (const float*)d_in[0];
    const float* w    = (const float*)d_in[1];
    const float* bias = (const float*)d_in[2];
    // d_in[3] = fm (int32) -- analytic, unused.
    float* out = (float*)d_out;

    dim3 grid(16 * (2048 / BTILE));   // 2048 blocks, 8/CU (LDS 20 KB x 8 = 160 KB)
    dim3 block(128);                  // 2 waves: f 0-7 and f 8-15
    hypercube_kernel<<<grid, block, 0, stream>>>(x, w, bias, out);
}